// Round 16
// baseline (152.367 us; speedup 1.0000x reference)
//
#include <hip/hip_runtime.h>
#include <math.h>

typedef unsigned short ushort_t;
typedef unsigned char  uchar_t;
typedef __attribute__((ext_vector_type(8))) short short8v;
typedef __attribute__((ext_vector_type(4))) float f32x4;
typedef __attribute__((ext_vector_type(2))) long l64x2;

#define KCOMP 128
#define DF    1024
#define LF    16
#define NPTS  16384
#define LOG2PI 1.8378770664093453f

// ---------------- full-path ws layout (bytes) ----------------
#define XQ_OFF    ((size_t)0)
#define XQ_BYTES  ((size_t)NPTS*DF)              // 16,777,216 fp8 (K-permuted)
#define BQ_OFF    (XQ_OFF + XQ_BYTES)
#define BQ_BYTES  ((size_t)2048*DF)              // 2,097,152 fp8 (K-permuted)
#define BSK_OFF   (BQ_OFF + BQ_BYTES)
#define BSK_BYTES ((size_t)KCOMP*2*DF*2)         // 524,288 bf16
#define CSK_OFF   (BSK_OFF + BSK_BYTES)
#define FULL_NEED (CSK_OFF + 512)

__device__ __forceinline__ ushort_t f2bf(float f) {
  union { float f; unsigned u; } v; v.f = f;
  unsigned u = v.u;
  return (ushort_t)((u + 0x7FFFu + ((u >> 16) & 1u)) >> 16);
}

#define GLOAD16(gp, lp) __builtin_amdgcn_global_load_lds( \
  (const __attribute__((address_space(1))) unsigned int*)(gp), \
  (__attribute__((address_space(3))) unsigned int*)(lp), 16, 0, 0)

// DPP reduce-add within 16-lane rows (VALU only, no LDS)
#define DPPADD(x, ctrl) do { \
  int _yi = __builtin_amdgcn_update_dpp(0, __float_as_int(x), ctrl, 0xF, 0xF, true); \
  (x) += __int_as_float(_yi); } while (0)

// ---------------------------------------------------------------------------
// pre_v3 (R14-verified, unchanged)
// ---------------------------------------------------------------------------
__global__ __launch_bounds__(1024) void mfa_pre(
    const float* __restrict__ PI, const float* __restrict__ MU,
    const float* __restrict__ A, const float* __restrict__ Dm,
    uchar_t* __restrict__ Bq, ushort_t* __restrict__ Bsk,
    float* __restrict__ csk)
{
  const int k = blockIdx.x, t = threadIdx.x;      // t in [0,1024)
  __shared__ float As[DF*LF];      // 64 KB, As[d*16 + l]
  __shared__ float iDs[DF];
  __shared__ float MUs[DF];
  __shared__ float red[1024];
  __shared__ float bpart[4][16];
  __shared__ float R[16][17];
  __shared__ float rinv_s[16], zsh[16], bsh[16];
  __shared__ float sc_sumlog, sc_c3;

  {
    const float4* Ag = (const float4*)(A + (size_t)k*DF*LF);
    float4* Al = (float4*)As;
    #pragma unroll
    for (int i = 0; i < 4; ++i) Al[t + i*1024] = Ag[t + i*1024];
    float dv = Dm[(size_t)k*DF + t];
    iDs[t] = 1.f/(dv*dv);
    MUs[t] = MU[(size_t)k*DF + t];
  }
  __syncthreads();

  const int e = t & 255, q = t >> 8;
  const int tl = e >> 4, tm = e & 15;
  {
    float acc = 0.f;
    const int d0 = q*256;
    #pragma unroll 4
    for (int dd = 0; dd < 256; ++dd) {
      int d = d0 + dd;
      acc = fmaf(As[d*16+tl]*iDs[d], As[d*16+tm], acc);
    }
    red[t] = acc;
  }
  if (e < 16) {
    float accb = 0.f;
    const int d0 = q*256;
    for (int dd = 0; dd < 256; ++dd) {
      int d = d0 + dd;
      accb = fmaf(iDs[d]*MUs[d], As[d*16+e], accb);
    }
    bpart[q][e] = accb;
  }
  __syncthreads();
  if (q == 0) {
    float s = red[e] + red[e+256] + red[e+512] + red[e+768];
    R[tl][tm] = s + (tl == tm ? 1.f : 0.f);
  }
  if (t < 16) bsh[t] = bpart[0][t] + bpart[1][t] + bpart[2][t] + bpart[3][t];
  __syncthreads();

  red[t] = iDs[t]*MUs[t]*MUs[t];
  __syncthreads();
  if (t < 256) red[t] = red[t] + red[t+256] + red[t+512] + red[t+768];
  __syncthreads();
  if (t < 64) red[t] = red[t] + red[t+64] + red[t+128] + red[t+192];
  __syncthreads();
  if (t == 0) { float s = 0.f; for (int i = 0; i < 64; ++i) s += red[i]; sc_c3 = s; }
  __syncthreads();
  red[t] = logf(iDs[t]);
  __syncthreads();
  if (t < 256) red[t] = red[t] + red[t+256] + red[t+512] + red[t+768];
  __syncthreads();
  if (t < 64) red[t] = red[t] + red[t+64] + red[t+128] + red[t+192];
  __syncthreads();
  if (t == 0) { float s = 0.f; for (int i = 0; i < 64; ++i) s += red[i]; sc_sumlog = s; }

  for (int j = 0; j < 16; ++j) {
    __syncthreads();
    if (t == j) {
      float s = R[j][j];
      for (int i = 0; i < j; ++i) s -= R[j][i]*R[j][i];
      float rj = sqrtf(s);
      R[j][j] = rj; rinv_s[j] = 1.f/rj;
    }
    __syncthreads();
    if (t < 16 && t > j) {
      float s = R[t][j];
      for (int i = 0; i < j; ++i) s -= R[t][i]*R[j][i];
      R[t][j] = s * rinv_s[j];
    }
  }
  __syncthreads();
  if (t == 0) {
    float ldet = 0.f;
    for (int j = 0; j < 16; ++j) ldet += 2.f*logf(R[j][j]);
    float w[16], z[16];
    for (int j = 0; j < 16; ++j) {
      float s = bsh[j];
      for (int i = 0; i < j; ++i) s -= R[j][i]*w[i];
      w[j] = s*rinv_s[j];
    }
    for (int j = 15; j >= 0; --j) {
      float s = w[j];
      for (int i = j+1; i < 16; ++i) s -= R[i][j]*z[i];
      z[j] = s*rinv_s[j];
      zsh[j] = z[j];
    }
    float muh = sc_c3;
    for (int l = 0; l < 16; ++l) muh -= bsh[l]*zsh[l];
    csk[k] = PI[k] - 0.5f*((float)DF*LOG2PI + ldet - sc_sumlog) - 0.5f*muh;
  }
  __syncthreads();

  {
    const int d = t;
    float iD = iDs[d];
    float mu = MUs[d];
    float v[16], gg[16];
    #pragma unroll
    for (int l = 0; l < 16; ++l) v[l] = iD * A[((size_t)k*DF + d)*LF + l];
    #pragma unroll
    for (int j = 0; j < 16; ++j) {
      float s = v[j];
      #pragma unroll
      for (int i = 0; i < 16; ++i) if (i < j) s -= R[j][i]*gg[i];
      gg[j] = s * rinv_s[j];
    }
    float h = iD*mu;
    #pragma unroll
    for (int l = 0; l < 16; ++l) h -= v[l]*zsh[l];
    const int dd = d & 63;
    const size_t poff = (size_t)(d & ~63) + ((dd >> 3) & 3)*16 + (dd >> 5)*8 + (dd & 7);
    #pragma unroll
    for (int l = 0; l < 16; ++l) {
      int r8 = __builtin_amdgcn_cvt_pk_fp8_f32(gg[l], gg[l], 0, false);
      Bq[(size_t)(k*16 + l)*DF + poff] = (uchar_t)(r8 & 0xFF);
    }
    Bsk[(size_t)k*2*DF + d]      = f2bf(-2.f*h);
    Bsk[(size_t)k*2*DF + DF + d] = f2bf(iD);
  }
}

// ---------------------------------------------------------------------------
// sk6 (R15-verified, unchanged): per 32-row block, 512 blocks x 256 thr.
// ---------------------------------------------------------------------------
__global__ __launch_bounds__(256) void mfa_sk6(
    const float* __restrict__ x, const ushort_t* __restrict__ Bsk,
    const float* __restrict__ csk, uchar_t* __restrict__ xq,
    float* __restrict__ out)
{
  __shared__ ushort_t xs[2048];
  __shared__ ushort_t x2s[2048];
  __shared__ ushort_t Bs[16384];
  const int t = threadIdx.x, lane = t & 63, wid = t >> 6;
  const int wc = wid;
  const int lr = lane & 15, lh = lane >> 4;
  const int n0 = blockIdx.x * 32;
  const int xr = t >> 3, c8 = t & 7;

  f32x4 acc[2][2] = {};

  float4 v0, v1;
  {
    const float* xp = x + (size_t)(n0 + xr)*DF + c8*8;
    v0 = ((const float4*)xp)[0]; v1 = ((const float4*)xp)[1];
  }

  for (int tt = 0; tt < 16; ++tt) {
    const int d0 = tt * 64;
    __syncthreads();
    long xq_pack;
    {
      float e[8] = {v0.x,v0.y,v0.z,v0.w, v1.x,v1.y,v1.z,v1.w};
      short8v b, qv;
      #pragma unroll
      for (int i = 0; i < 8; ++i) {
        b[i]  = (short)f2bf(e[i]);
        qv[i] = (short)f2bf(e[i]*e[i]);
      }
      const int ch = c8 ^ (xr & 7);
      *(short8v*)&xs[xr*64 + ch*8]  = b;
      *(short8v*)&x2s[xr*64 + ch*8] = qv;
      int p0 = 0, p1 = 0;
      p0 = __builtin_amdgcn_cvt_pk_fp8_f32(e[0], e[1], p0, false);
      p0 = __builtin_amdgcn_cvt_pk_fp8_f32(e[2], e[3], p0, true);
      p1 = __builtin_amdgcn_cvt_pk_fp8_f32(e[4], e[5], p1, false);
      p1 = __builtin_amdgcn_cvt_pk_fp8_f32(e[6], e[7], p1, true);
      xq_pack = (long)(((unsigned long long)(unsigned)p1 << 32) | (unsigned)p0);
    }
    #pragma unroll
    for (int j = 0; j < 8; ++j) {
      int id = wid*8 + j;
      int vc = id*8 + (lane >> 3);
      int g = (lane & 7) ^ (vc & 7);
      const ushort_t* src = (vc < 128)
        ? Bsk + (size_t)vc*(2*DF) + d0 + g*8
        : Bsk + (size_t)(vc - 128)*(2*DF) + DF + d0 + g*8;
      GLOAD16(src, (char*)Bs + id*1024);
    }
    asm volatile("s_waitcnt vmcnt(0) lgkmcnt(0)" ::: "memory");
    __syncthreads();
    {
      const size_t perm = (size_t)(c8 & 3)*16 + (size_t)(c8 >> 2)*8;
      *(long*)&xq[(size_t)(n0 + xr)*DF + d0 + perm] = xq_pack;
    }
    if (tt < 15) {
      const float* xp = x + (size_t)(n0 + xr)*DF + (d0 + 64) + c8*8;
      v0 = ((const float4*)xp)[0]; v1 = ((const float4*)xp)[1];
    }
    __builtin_amdgcn_sched_barrier(0);
    #pragma unroll
    for (int ks = 0; ks < 2; ++ks) {
      const int cterm = ((ks*4 + lh) ^ (lr & 7)) * 8;
      short8v a_[2], a2_[2], bh[2], bi[2];
      #pragma unroll
      for (int rb = 0; rb < 2; ++rb) {
        int row = rb*16 + lr;
        a_[rb]  = *(const short8v*)&xs[row*64 + cterm];
        a2_[rb] = *(const short8v*)&x2s[row*64 + cterm];
      }
      #pragma unroll
      for (int cb = 0; cb < 2; ++cb) {
        int vh = wc*32 + cb*16 + lr;
        bh[cb] = *(const short8v*)&Bs[vh*64 + cterm];
        bi[cb] = *(const short8v*)&Bs[(128 + vh)*64 + cterm];
      }
      #pragma unroll
      for (int cb = 0; cb < 2; ++cb)
        #pragma unroll
        for (int rb = 0; rb < 2; ++rb) {
          acc[rb][cb] = __builtin_amdgcn_mfma_f32_16x16x32_bf16(a_[rb],  bh[cb], acc[rb][cb], 0,0,0);
          acc[rb][cb] = __builtin_amdgcn_mfma_f32_16x16x32_bf16(a2_[rb], bi[cb], acc[rb][cb], 0,0,0);
        }
    }
  }
  #pragma unroll
  for (int cb = 0; cb < 2; ++cb) {
    int comp = wc*32 + cb*16 + lr;
    float ck = csk[comp];
    #pragma unroll
    for (int rb = 0; rb < 2; ++rb)
      #pragma unroll
      for (int j = 0; j < 4; ++j) {
        int row = n0 + rb*16 + lh*4 + j;
        out[(size_t)row*KCOMP + comp] = ck - 0.5f*acc[rb][cb][j];
      }
  }
}

// ---------------------------------------------------------------------------
// gemm12: gemm11's verified machinery at 128x64 wave tile (LDS-read intensity
// lever: 12 b128 reads per 64 MFMAs vs 8 per 32). 256 thr / 4 waves (2Mx2N),
// block tile 256x128, acc 8x4. 3-slot rotation (24KB slots: A 16KB | B 8KB),
// vmcnt(6) gate, 1 barrier/tile, no lgkm drain (same completion argument).
// 72KB LDS + launch_bounds(256,2) -> 2 blocks/CU.
// ---------------------------------------------------------------------------
__global__ __launch_bounds__(256, 2) void mfa_gemm12(
    const uchar_t* __restrict__ xq, const uchar_t* __restrict__ Bq,
    float* __restrict__ out)
{
  __shared__ uchar_t smem[73728];   // 3 slots x 24KB (A 16KB | B 8KB)
  const int t = threadIdx.x, lane = t & 63, wid = t >> 6;  // 4 waves
  const int wm = wid & 1, wn = wid >> 1;
  const int lr = lane & 15, lh = lane >> 4;

  const int bid = blockIdx.x;            // 1024 = 64 rb x 16 cb
  const int xcd = bid & 7, ib = bid >> 3;
  const int rb = xcd*8 + (ib >> 4);      // XCD owns 8 contiguous row-bands
  const int cb = ib & 15;
  const int n0 = rb * 256, c0 = cb * 128;

  f32x4 acc[8][4] = {};

  // staging: 24 x 1KB instrs per K-tile (A ids 0..15, B ids 16..23), 6/wave.
  const int js = (((lane & 3) ^ ((lane >> 3) & 3)) * 16);
  const uchar_t* srcP[6]; int dstO[6];
  #pragma unroll
  for (int q = 0; q < 6; ++q) {
    int id = wid*6 + q;
    if (id < 16) {
      int r = id*16 + (lane >> 2);
      srcP[q] = xq + (size_t)(n0 + r)*DF + js;
      dstO[q] = id*1024;
    } else {
      int cr = (id - 16)*16 + (lane >> 2);
      srcP[q] = Bq + (size_t)(c0 + cr)*DF + js;
      dstO[q] = 16384 + (id - 16)*1024;
    }
  }
  const int rsw = (lh ^ ((lr >> 1) & 3)) * 16;
  const int aO = (wm*128 + lr)*64 + rsw;           // + rt*1024, rt 0..8
  const int bO = 16384 + (wn*64 + lr)*64 + rsw;    // + ct*1024, ct 0..4

  #define STAGE12(slot, tt_) do { \
    _Pragma("unroll") \
    for (int q = 0; q < 6; ++q) \
      GLOAD16(srcP[q] + (tt_)*64, (char*)smem + (slot)*24576 + dstO[q] + ((lane)*16 & 1023)); \
  } while (0)

  STAGE12(0, 0);
  STAGE12(1, 1);

  int slot_r = 0;    // slot holding tile tt
  int slot_s = 2;    // slot to restage with tile tt+2
  for (int tt = 0; tt < 16; ++tt) {
    if (tt < 15) asm volatile("s_waitcnt vmcnt(6)" ::: "memory");
    else         asm volatile("s_waitcnt vmcnt(0)" ::: "memory");
    __builtin_amdgcn_s_barrier();
    if (tt + 2 <= 15) STAGE12(slot_s, tt + 2);

    const char* lb = (const char*)smem + slot_r * 24576;
    l64x2 a2[8], b2[4];
    #pragma unroll
    for (int rt = 0; rt < 8; ++rt) a2[rt] = *(const l64x2*)(lb + aO + rt*1024);
    #pragma unroll
    for (int ct = 0; ct < 4; ++ct) b2[ct] = *(const l64x2*)(lb + bO + ct*1024);
    // no lgkm drain: restaged slot's reads were consumed by last iter's MFMAs

    __builtin_amdgcn_s_setprio(1);
    #pragma unroll
    for (int ct = 0; ct < 4; ++ct)
      #pragma unroll
      for (int rt = 0; rt < 8; ++rt)
        acc[rt][ct] = __builtin_amdgcn_mfma_f32_16x16x32_fp8_fp8(a2[rt][0], b2[ct][0], acc[rt][ct], 0,0,0);
    #pragma unroll
    for (int ct = 0; ct < 4; ++ct)
      #pragma unroll
      for (int rt = 0; rt < 8; ++rt)
        acc[rt][ct] = __builtin_amdgcn_mfma_f32_16x16x32_fp8_fp8(a2[rt][1], b2[ct][1], acc[rt][ct], 0,0,0);
    __builtin_amdgcn_s_setprio(0);

    slot_r = (slot_r == 2) ? 0 : slot_r + 1;
    slot_s = (slot_s == 2) ? 0 : slot_s + 1;
  }

  // ---- epilogue: per-(row,comp) sum over 16 cols via DPP, out += 0.5*sum ----
  #pragma unroll
  for (int ct = 0; ct < 4; ++ct) {
    const int comp = cb*8 + wn*4 + ct;
    #pragma unroll
    for (int rt = 0; rt < 8; ++rt) {
      #pragma unroll
      for (int j = 0; j < 4; ++j) {
        float v = acc[rt][ct][j];
        float sq = v*v;
        DPPADD(sq, 0xB1);
        DPPADD(sq, 0x4E);
        DPPADD(sq, 0x124);
        DPPADD(sq, 0x128);
        if (lr == 0) {
          int row = n0 + wm*128 + rt*16 + lh*4 + j;
          size_t idx = (size_t)row * KCOMP + comp;
          out[idx] = out[idx] + 0.5f*sq;
        }
      }
    }
  }
}

// ===========================================================================
// Fallback path (round-2 kernels, needs ~4.8 MB ws) — used if ws too small
// ===========================================================================
#define FB_NG 8
#define FB_CG 288
#define FB_BN 128
#define FB_DT 32
#define FB_PITCH 40
#define FB_BMAT_ELEMS ((size_t)(FB_NG*FB_CG)*DF)
#define FB_CST_OFF (FB_BMAT_ELEMS*2)
#define FB_MUH_OFF (FB_CST_OFF + 512)

__global__ __launch_bounds__(256) void fb_pre(
    const float* __restrict__ PI, const float* __restrict__ MU,
    const float* __restrict__ A, const float* __restrict__ Dm,
    ushort_t* __restrict__ Bmat, float* __restrict__ cst, float* __restrict__ muh)
{
  const int k = blockIdx.x, t = threadIdx.x;
  const int tl = t >> 4, tm = t & 15;
  __shared__ float As[16][16], iDsh[16], MUsh[16];
  __shared__ float R[16][17], rinv[16], zsh[16], bsh[16];
  __shared__ float red[256];

  float accL = 0.f, accb = 0.f, slog = 0.f;
  for (int d0 = 0; d0 < DF; d0 += 16) {
    __syncthreads();
    As[tl][tm] = A[((size_t)k*DF + d0 + tl)*LF + tm];
    if (t < 16) {
      float dv = Dm[k*DF + d0 + t];
      iDsh[t] = 1.f/(dv*dv);
      MUsh[t] = MU[k*DF + d0 + t];
    }
    __syncthreads();
    #pragma unroll
    for (int dd = 0; dd < 16; ++dd)
      accL = fmaf(As[dd][tl]*iDsh[dd], As[dd][tm], accL);
    if (tm == 0) {
      #pragma unroll
      for (int dd = 0; dd < 16; ++dd)
        accb = fmaf(iDsh[dd]*MUsh[dd], As[dd][tl], accb);
    }
    if (t < 16) slog += logf(iDsh[t]);
  }
  __syncthreads();
  R[tl][tm] = accL + (tl == tm ? 1.f : 0.f);
  if (tm == 0) bsh[tl] = accb;
  red[t] = (t < 16) ? slog : 0.f;
  __syncthreads();
  float sumlogiD = 0.f;
  if (t == 0) { for (int i = 0; i < 16; ++i) sumlogiD += red[i]; }

  for (int j = 0; j < 16; ++j) {
    if (t == j) {
      float s = R[j][j];
      for (int i = 0; i < j; ++i) s -= R[j][i]*R[j][i];
      float rj = sqrtf(s);
      R[j][j] = rj; rinv[j] = 1.f/rj;
    }
    __syncthreads();
    if (t < 16 && t > j) {
      float s = R[t][j];
      for (int i = 0; i < j; ++i) s -= R[t][i]*R[j][i];
      R[t][j] = s * rinv[j];
    }
    __syncthreads();
  }

  float ldet = 0.f;
  if (t == 0) {
    #pragma unroll
    for (int j = 0; j < 16; ++j) ldet += 2.f*logf(R[j][j]);
    float w[16], z[16];
    #pragma unroll
    for (int j = 0; j < 16; ++j) {
      float s = bsh[j];
      #pragma unroll
      for (int i = 0; i < 16; ++i) if (i < j) s -= R[j][i]*w[i];
      w[j] = s*rinv[j];
    }
    #pragma unroll
    for (int j = 15; j >= 0; --j) {
      float s = w[j];
      #pragma unroll
      for (int i = 0; i < 16; ++i) if (i > j) s -= R[i][j]*z[i];
      z[j] = s*rinv[j];
      zsh[j] = z[j];
    }
  }
  __syncthreads();

  const int g = k >> 4, kl = k & 15;
  ushort_t* Bgp = Bmat + (size_t)g*FB_CG*DF;
  float muhp = 0.f;
  for (int itr = 0; itr < 4; ++itr) {
    int d = t + itr*256;
    float dv = Dm[k*DF + d];
    float iD = 1.f/(dv*dv);
    float mu = MU[k*DF + d];
    float v[16], gg[16];
    #pragma unroll
    for (int l = 0; l < 16; ++l) v[l] = iD * A[((size_t)k*DF + d)*LF + l];
    #pragma unroll
    for (int j = 0; j < 16; ++j) {
      float s = v[j];
      #pragma unroll
      for (int i = 0; i < 16; ++i) if (i < j) s -= R[j][i]*gg[i];
      gg[j] = s * rinv[j];
    }
    float h = iD*mu;
    #pragma unroll
    for (int l = 0; l < 16; ++l) h -= v[l]*zsh[l];
    muhp = fmaf(mu, h, muhp);
    #pragma unroll
    for (int l = 0; l < 16; ++l)
      Bgp[(size_t)(kl*16 + l)*DF + d] = f2bf(gg[l]);
    Bgp[(size_t)(256 + kl)*DF + d] = f2bf(h);
    Bgp[(size_t)(272 + kl)*DF + d] = f2bf(iD);
  }
  red[t] = muhp;
  __syncthreads();
  for (int s = 128; s > 0; s >>= 1) {
    if (t < s) red[t] += red[t + s];
    __syncthreads();
  }
  if (t == 0) {
    muh[k] = red[0];
    cst[k] = PI[k] - 0.5f*((float)DF*LOG2PI + ldet - sumlogiD);
  }
}

__global__ __launch_bounds__(512, 2) void fb_main(
    const float* __restrict__ x, const ushort_t* __restrict__ Bmat,
    const float* __restrict__ cst, const float* __restrict__ muh,
    float* __restrict__ out)
{
  __shared__ __align__(16) ushort_t smem[2*FB_BN*FB_PITCH + FB_CG*FB_PITCH];
  ushort_t* xs  = smem;
  ushort_t* x2s = smem + FB_BN*FB_PITCH;
  ushort_t* Bs  = smem + 2*FB_BN*FB_PITCH;

  const int t = threadIdx.x;
  const int lane = t & 63, wid = t >> 6;
  const int wr = wid & 3, wc = wid >> 2;
  const int lr = lane & 15, lh = lane >> 4;
  const int n0 = blockIdx.x * FB_BN;
  const int g  = blockIdx.y;

  f32x4 acc[2][9] = {};
  const int srow = t >> 2, sc = t & 3;

  int xoff[2];
  #pragma unroll
  for (int rt = 0; rt < 2; ++rt)
    xoff[rt] = (wr*32 + rt*16 + lr)*FB_PITCH + lh*8;
  int boff[9];
  #pragma unroll
  for (int ct = 0; ct < 9; ++ct)
    boff[ct] = (wc*144 + ct*16 + lr)*FB_PITCH + lh*8;

  for (int d0 = 0; d0 < DF; d0 += FB_DT) {
    __syncthreads();
    {
      const float* xp = x + (size_t)(n0 + srow)*DF + d0 + sc*8;
      float4 v0 = *(const float4*)xp;
      float4 v1 = *(const float4*)(xp + 4);
      float e[8] = {v0.x,v0.y,v0.z,v0.w,v1.x,v1.y,v1.z,v1.w};
      short8v xv, qv;
      #pragma unroll
      for (int i = 0; i < 8; ++i) {
        xv[i] = (short)f2bf(e[i]);
        qv[i] = (short)f2bf(e[i]*e[i]);
      }
      *(short8v*)&xs[srow*FB_PITCH + sc*8]  = xv;
      *(short8v*)&x2s[srow*FB_PITCH + sc*8] = qv;
    }
    for (int u = t; u < FB_CG*4; u += 512) {
      int col = u >> 2, c = u & 3;
      *(short8v*)&Bs[col*FB_PITCH + c*8] =
        *(const short8v*)&Bmat[((size_t)(g*FB_CG + col))*DF + d0 + c*8];
    }
    __syncthreads();

    short8v xf[2];
    #pragma unroll
    for (int rt = 0; rt < 2; ++rt) xf[rt] = *(short8v*)&xs[xoff[rt]];
    #pragma unroll
    for (int ct = 0; ct < 8; ++ct) {
      short8v bfr = *(short8v*)&Bs[boff[ct]];
      #pragma unroll
      for (int rt = 0; rt < 2; ++rt)
        acc[rt][ct] = __builtin_amdgcn_mfma_f32_16x16x32_bf16(xf[rt], bfr, acc[rt][ct], 0, 0, 0);
    }
    {
      short8v bfr = *(short8v*)&Bs[boff[8]];
      short8v a0 = xf[0], a1 = xf[1];
      if (wc) {
        a0 = *(short8v*)&x2s[xoff[0]];
        a1 = *(short8v*)&x2s[xoff[1]];
      }
      acc[0][8] = __builtin_amdgcn_mfma_f32_16x16x32_bf16(a0, bfr, acc[0][8], 0, 0, 0);
      acc[1][8] = __builtin_amdgcn_mfma_f32_16x16x32_bf16(a1, bfr, acc[1][8], 0, 0, 0);
    }
  }

  __syncthreads();
  float* s1v = (float*)smem;
  float* s2h = s1v + FB_BN*17;
  if (wc == 1) {
    #pragma unroll
    for (int rt = 0; rt < 2; ++rt)
      #pragma unroll
      for (int j = 0; j < 4; ++j) {
        int row = wr*32 + rt*16 + lh*4 + j;
        s2h[row*17 + lr] = acc[rt][7][j];
        s1v[row*17 + lr] = acc[rt][8][j];
      }
  }
  __syncthreads();

  const int nyt = wc ? 7 : 9;
  #pragma unroll
  for (int ct = 0; ct < 9; ++ct) {
    if (ct < nyt) {
      int comp = wc*9 + ct;
      int kk = g*16 + comp;
      float cstk = cst[kk], muhk = muh[kk];
      #pragma unroll
      for (int rt = 0; rt < 2; ++rt)
        #pragma unroll
        for (int j = 0; j < 4; ++j) {
          float yv = acc[rt][ct][j];
          float sq = yv*yv;
          sq += __shfl_xor(sq, 1);
          sq += __shfl_xor(sq, 2);
          sq += __shfl_xor(sq, 4);
          sq += __shfl_xor(sq, 8);
          int row = wr*32 + rt*16 + lh*4 + j;
          float s1 = s1v[row*17 + comp];
          float s2 = s2h[row*17 + comp];
          float res = cstk - 0.5f*(s1 - sq - 2.f*s2 + muhk);
          if (lr == 0) out[(size_t)(n0 + row)*KCOMP + kk] = res;
        }
    }
  }
}

// ===========================================================================
extern "C" void kernel_launch(void* const* d_in, const int* in_sizes, int n_in,
                              void* d_out, int out_size, void* d_ws, size_t ws_size,
                              hipStream_t stream) {
  const float* x  = (const float*)d_in[0];
  const float* PI = (const float*)d_in[1];
  const float* MU = (const float*)d_in[2];
  const float* A  = (const float*)d_in[3];
  const float* Dm = (const float*)d_in[4];
  float* out = (float*)d_out;

  if (ws_size >= FULL_NEED) {
    uchar_t* xq   = (uchar_t*)((char*)d_ws + XQ_OFF);
    uchar_t* Bq   = (uchar_t*)((char*)d_ws + BQ_OFF);
    ushort_t* Bsk = (ushort_t*)((char*)d_ws + BSK_OFF);
    float* csk    = (float*)((char*)d_ws + CSK_OFF);

    mfa_pre<<<dim3(KCOMP), dim3(1024), 0, stream>>>(PI, MU, A, Dm, Bq, Bsk, csk);
    mfa_sk6<<<dim3(NPTS/32), dim3(256), 0, stream>>>(x, Bsk, csk, xq, out);
    mfa_gemm12<<<dim3((NPTS/256)*(2048/128)), dim3(256), 0, stream>>>(xq, Bq, out);
  } else {
    ushort_t* Bmat = (ushort_t*)d_ws;
    float* cstp = (float*)((char*)d_ws + FB_CST_OFF);
    float* muhp = (float*)((char*)d_ws + FB_MUH_OFF);
    fb_pre<<<dim3(KCOMP), dim3(256), 0, stream>>>(PI, MU, A, Dm, Bmat, cstp, muhp);
    fb_main<<<dim3(NPTS/FB_BN, FB_NG), dim3(512), 0, stream>>>(x, Bmat, cstp, muhp, out);
  }
}

// Round 17
// 128.019 us; speedup vs baseline: 1.1902x; 1.1902x over previous
//
#include <hip/hip_runtime.h>
#include <math.h>

typedef unsigned short ushort_t;
typedef unsigned char  uchar_t;
typedef __attribute__((ext_vector_type(8))) short short8v;
typedef __attribute__((ext_vector_type(4))) float f32x4;
typedef __attribute__((ext_vector_type(2))) long l64x2;

#define KCOMP 128
#define DF    1024
#define LF    16
#define NPTS  16384
#define LOG2PI 1.8378770664093453f

// ---------------- full-path ws layout (bytes) ----------------
#define XQ_OFF    ((size_t)0)
#define XQ_BYTES  ((size_t)NPTS*DF)              // 16,777,216 fp8 (K-permuted)
#define BQ_OFF    (XQ_OFF + XQ_BYTES)
#define BQ_BYTES  ((size_t)2048*DF)              // 2,097,152 fp8 (K-permuted)
#define BSK_OFF   (BQ_OFF + BQ_BYTES)
#define BSK_BYTES ((size_t)KCOMP*2*DF*2)         // 524,288 bf16
#define CSK_OFF   (BSK_OFF + BSK_BYTES)
#define FULL_NEED (CSK_OFF + 512)

__device__ __forceinline__ ushort_t f2bf(float f) {
  union { float f; unsigned u; } v; v.f = f;
  unsigned u = v.u;
  return (ushort_t)((u + 0x7FFFu + ((u >> 16) & 1u)) >> 16);
}

#define GLOAD16(gp, lp) __builtin_amdgcn_global_load_lds( \
  (const __attribute__((address_space(1))) unsigned int*)(gp), \
  (__attribute__((address_space(3))) unsigned int*)(lp), 16, 0, 0)

// DPP reduce-add within 16-lane rows (VALU only, no LDS)
#define DPPADD(x, ctrl) do { \
  int _yi = __builtin_amdgcn_update_dpp(0, __float_as_int(x), ctrl, 0xF, 0xF, true); \
  (x) += __int_as_float(_yi); } while (0)

// ---------------------------------------------------------------------------
// pre_v3 (R14-verified): 128 blocks x 1024 thr. Stage A/iD/MU to LDS once;
// Gram 4-way + reduce; Cholesky; z; per-d (1/thread): G col-solve, h ->
// Bq fp8 (K-permuted) + Bsk bf16 [-2h ; iD] + csk.
// ---------------------------------------------------------------------------
__global__ __launch_bounds__(1024) void mfa_pre(
    const float* __restrict__ PI, const float* __restrict__ MU,
    const float* __restrict__ A, const float* __restrict__ Dm,
    uchar_t* __restrict__ Bq, ushort_t* __restrict__ Bsk,
    float* __restrict__ csk)
{
  const int k = blockIdx.x, t = threadIdx.x;      // t in [0,1024)
  __shared__ float As[DF*LF];      // 64 KB, As[d*16 + l]
  __shared__ float iDs[DF];
  __shared__ float MUs[DF];
  __shared__ float red[1024];
  __shared__ float bpart[4][16];
  __shared__ float R[16][17];
  __shared__ float rinv_s[16], zsh[16], bsh[16];
  __shared__ float sc_sumlog, sc_c3;

  {
    const float4* Ag = (const float4*)(A + (size_t)k*DF*LF);
    float4* Al = (float4*)As;
    #pragma unroll
    for (int i = 0; i < 4; ++i) Al[t + i*1024] = Ag[t + i*1024];
    float dv = Dm[(size_t)k*DF + t];
    iDs[t] = 1.f/(dv*dv);
    MUs[t] = MU[(size_t)k*DF + t];
  }
  __syncthreads();

  const int e = t & 255, q = t >> 8;
  const int tl = e >> 4, tm = e & 15;
  {
    float acc = 0.f;
    const int d0 = q*256;
    #pragma unroll 4
    for (int dd = 0; dd < 256; ++dd) {
      int d = d0 + dd;
      acc = fmaf(As[d*16+tl]*iDs[d], As[d*16+tm], acc);
    }
    red[t] = acc;
  }
  if (e < 16) {
    float accb = 0.f;
    const int d0 = q*256;
    for (int dd = 0; dd < 256; ++dd) {
      int d = d0 + dd;
      accb = fmaf(iDs[d]*MUs[d], As[d*16+e], accb);
    }
    bpart[q][e] = accb;
  }
  __syncthreads();
  if (q == 0) {
    float s = red[e] + red[e+256] + red[e+512] + red[e+768];
    R[tl][tm] = s + (tl == tm ? 1.f : 0.f);
  }
  if (t < 16) bsh[t] = bpart[0][t] + bpart[1][t] + bpart[2][t] + bpart[3][t];
  __syncthreads();

  red[t] = iDs[t]*MUs[t]*MUs[t];
  __syncthreads();
  if (t < 256) red[t] = red[t] + red[t+256] + red[t+512] + red[t+768];
  __syncthreads();
  if (t < 64) red[t] = red[t] + red[t+64] + red[t+128] + red[t+192];
  __syncthreads();
  if (t == 0) { float s = 0.f; for (int i = 0; i < 64; ++i) s += red[i]; sc_c3 = s; }
  __syncthreads();
  red[t] = logf(iDs[t]);
  __syncthreads();
  if (t < 256) red[t] = red[t] + red[t+256] + red[t+512] + red[t+768];
  __syncthreads();
  if (t < 64) red[t] = red[t] + red[t+64] + red[t+128] + red[t+192];
  __syncthreads();
  if (t == 0) { float s = 0.f; for (int i = 0; i < 64; ++i) s += red[i]; sc_sumlog = s; }

  for (int j = 0; j < 16; ++j) {
    __syncthreads();
    if (t == j) {
      float s = R[j][j];
      for (int i = 0; i < j; ++i) s -= R[j][i]*R[j][i];
      float rj = sqrtf(s);
      R[j][j] = rj; rinv_s[j] = 1.f/rj;
    }
    __syncthreads();
    if (t < 16 && t > j) {
      float s = R[t][j];
      for (int i = 0; i < j; ++i) s -= R[t][i]*R[j][i];
      R[t][j] = s * rinv_s[j];
    }
  }
  __syncthreads();
  if (t == 0) {
    float ldet = 0.f;
    for (int j = 0; j < 16; ++j) ldet += 2.f*logf(R[j][j]);
    float w[16], z[16];
    for (int j = 0; j < 16; ++j) {
      float s = bsh[j];
      for (int i = 0; i < j; ++i) s -= R[j][i]*w[i];
      w[j] = s*rinv_s[j];
    }
    for (int j = 15; j >= 0; --j) {
      float s = w[j];
      for (int i = j+1; i < 16; ++i) s -= R[i][j]*z[i];
      z[j] = s*rinv_s[j];
      zsh[j] = z[j];
    }
    float muh = sc_c3;
    for (int l = 0; l < 16; ++l) muh -= bsh[l]*zsh[l];
    csk[k] = PI[k] - 0.5f*((float)DF*LOG2PI + ldet - sc_sumlog) - 0.5f*muh;
  }
  __syncthreads();

  {
    const int d = t;
    float iD = iDs[d];
    float mu = MUs[d];
    float v[16], gg[16];
    #pragma unroll
    for (int l = 0; l < 16; ++l) v[l] = iD * A[((size_t)k*DF + d)*LF + l];
    #pragma unroll
    for (int j = 0; j < 16; ++j) {
      float s = v[j];
      #pragma unroll
      for (int i = 0; i < 16; ++i) if (i < j) s -= R[j][i]*gg[i];
      gg[j] = s * rinv_s[j];
    }
    float h = iD*mu;
    #pragma unroll
    for (int l = 0; l < 16; ++l) h -= v[l]*zsh[l];
    const int dd = d & 63;
    const size_t poff = (size_t)(d & ~63) + ((dd >> 3) & 3)*16 + (dd >> 5)*8 + (dd & 7);
    #pragma unroll
    for (int l = 0; l < 16; ++l) {
      int r8 = __builtin_amdgcn_cvt_pk_fp8_f32(gg[l], gg[l], 0, false);
      Bq[(size_t)(k*16 + l)*DF + poff] = (uchar_t)(r8 & 0xFF);
    }
    Bsk[(size_t)k*2*DF + d]      = f2bf(-2.f*h);
    Bsk[(size_t)k*2*DF + DF + d] = f2bf(iD);
  }
}

// ---------------------------------------------------------------------------
// sk6 (R15-verified): per 32-row block, 512 blocks x 256 thr (4 waves; wave
// wc covers all 32 rows x comps [wc*32, wc*32+32)). 2 blocks/CU.
// Convert x -> bf16/x^2 LDS + fp8 xq (K-permuted, post-drain store);
// out[n,c] = csk[c] - 0.5*( x.(-2h) + x^2.iD )  (bf16 MFMA).
// ---------------------------------------------------------------------------
__global__ __launch_bounds__(256) void mfa_sk6(
    const float* __restrict__ x, const ushort_t* __restrict__ Bsk,
    const float* __restrict__ csk, uchar_t* __restrict__ xq,
    float* __restrict__ out)
{
  __shared__ ushort_t xs[2048];     // [32][64] swizzled (8-elem chunk ^ row&7)
  __shared__ ushort_t x2s[2048];
  __shared__ ushort_t Bs[16384];    // [256 vcols][64] swizzled (0-127 h, 128-255 iD)
  const int t = threadIdx.x, lane = t & 63, wid = t >> 6;
  const int wc = wid;
  const int lr = lane & 15, lh = lane >> 4;
  const int n0 = blockIdx.x * 32;
  const int xr = t >> 3, c8 = t & 7;

  f32x4 acc[2][2] = {};

  float4 v0, v1;
  {
    const float* xp = x + (size_t)(n0 + xr)*DF + c8*8;
    v0 = ((const float4*)xp)[0]; v1 = ((const float4*)xp)[1];
  }

  for (int tt = 0; tt < 16; ++tt) {
    const int d0 = tt * 64;
    __syncthreads();                    // prev-iter LDS reads retired
    long xq_pack;
    {
      float e[8] = {v0.x,v0.y,v0.z,v0.w, v1.x,v1.y,v1.z,v1.w};
      short8v b, qv;
      #pragma unroll
      for (int i = 0; i < 8; ++i) {
        b[i]  = (short)f2bf(e[i]);
        qv[i] = (short)f2bf(e[i]*e[i]);
      }
      const int ch = c8 ^ (xr & 7);
      *(short8v*)&xs[xr*64 + ch*8]  = b;
      *(short8v*)&x2s[xr*64 + ch*8] = qv;
      int p0 = 0, p1 = 0;
      p0 = __builtin_amdgcn_cvt_pk_fp8_f32(e[0], e[1], p0, false);
      p0 = __builtin_amdgcn_cvt_pk_fp8_f32(e[2], e[3], p0, true);
      p1 = __builtin_amdgcn_cvt_pk_fp8_f32(e[4], e[5], p1, false);
      p1 = __builtin_amdgcn_cvt_pk_fp8_f32(e[6], e[7], p1, true);
      xq_pack = (long)(((unsigned long long)(unsigned)p1 << 32) | (unsigned)p0);
    }
    // ---- stage B tile (32KB): 32 ids, 8 per wave ----
    #pragma unroll
    for (int j = 0; j < 8; ++j) {
      int id = wid*8 + j;
      int vc = id*8 + (lane >> 3);
      int g = (lane & 7) ^ (vc & 7);
      const ushort_t* src = (vc < 128)
        ? Bsk + (size_t)vc*(2*DF) + d0 + g*8
        : Bsk + (size_t)(vc - 128)*(2*DF) + DF + d0 + g*8;
      GLOAD16(src, (char*)Bs + id*1024);
    }
    asm volatile("s_waitcnt vmcnt(0) lgkmcnt(0)" ::: "memory");
    __syncthreads();
    // ---- post-drain: xq store (fire-and-forget) + next-x prefetch ----
    {
      const size_t perm = (size_t)(c8 & 3)*16 + (size_t)(c8 >> 2)*8;
      *(long*)&xq[(size_t)(n0 + xr)*DF + d0 + perm] = xq_pack;
    }
    if (tt < 15) {
      const float* xp = x + (size_t)(n0 + xr)*DF + (d0 + 64) + c8*8;
      v0 = ((const float4*)xp)[0]; v1 = ((const float4*)xp)[1];
    }
    __builtin_amdgcn_sched_barrier(0);
    // ---- compute ----
    #pragma unroll
    for (int ks = 0; ks < 2; ++ks) {
      const int cterm = ((ks*4 + lh) ^ (lr & 7)) * 8;
      short8v a_[2], a2_[2], bh[2], bi[2];
      #pragma unroll
      for (int rb = 0; rb < 2; ++rb) {
        int row = rb*16 + lr;
        a_[rb]  = *(const short8v*)&xs[row*64 + cterm];
        a2_[rb] = *(const short8v*)&x2s[row*64 + cterm];
      }
      #pragma unroll
      for (int cb = 0; cb < 2; ++cb) {
        int vh = wc*32 + cb*16 + lr;
        bh[cb] = *(const short8v*)&Bs[vh*64 + cterm];
        bi[cb] = *(const short8v*)&Bs[(128 + vh)*64 + cterm];
      }
      #pragma unroll
      for (int cb = 0; cb < 2; ++cb)
        #pragma unroll
        for (int rb = 0; rb < 2; ++rb) {
          acc[rb][cb] = __builtin_amdgcn_mfma_f32_16x16x32_bf16(a_[rb],  bh[cb], acc[rb][cb], 0,0,0);
          acc[rb][cb] = __builtin_amdgcn_mfma_f32_16x16x32_bf16(a2_[rb], bi[cb], acc[rb][cb], 0,0,0);
        }
    }
  }
  // ---- epilogue ----
  #pragma unroll
  for (int cb = 0; cb < 2; ++cb) {
    int comp = wc*32 + cb*16 + lr;
    float ck = csk[comp];
    #pragma unroll
    for (int rb = 0; rb < 2; ++rb)
      #pragma unroll
      for (int j = 0; j < 4; ++j) {
        int row = n0 + rb*16 + lh*4 + j;
        out[(size_t)row*KCOMP + comp] = ck - 0.5f*acc[rb][cb][j];
      }
  }
}

// ---------------------------------------------------------------------------
// gemm11 (R12/R15-verified): out += 0.5 * sum_l y_l^2 ; y = xq . Bq^T
// (fp8 e4m3, f32 acc). 1024 blocks x 512 thr (8 waves 4Mx2N... wm/wn 2x4),
// wave 64x64 (acc 4x4). 3-slot LDS rotation (24KB slots), vmcnt(3) gate,
// 1 barrier/tile, C++ b128 reads (K-permuted pair layout), DPP epilogue.
// ---------------------------------------------------------------------------
__global__ __launch_bounds__(512, 4) void mfa_gemm11(
    const uchar_t* __restrict__ xq, const uchar_t* __restrict__ Bq,
    float* __restrict__ out)
{
  __shared__ uchar_t smem[73728];   // 3 slots x 24KB (A 8KB | B 16KB)
  const int t = threadIdx.x, lane = t & 63, wid = t >> 6;  // 8 waves
  const int wm = wid & 1, wn = wid >> 1;
  const int lr = lane & 15, lh = lane >> 4;

  const int bid = blockIdx.x;            // 1024 = 128 rb x 8 cb
  const int xcd = bid & 7, ib = bid >> 3;
  const int rb = xcd*16 + (ib >> 3);     // XCD owns 16 contiguous row-bands
  const int cb = ib & 7;
  const int n0 = rb * 128, c0 = cb * 256;

  f32x4 acc[4][4] = {};

  const int js = (((lane & 3) ^ ((lane >> 3) & 3)) * 16);
  const uchar_t* srcP[3]; int dstO[3];
  #pragma unroll
  for (int q = 0; q < 3; ++q) {
    int id = wid*3 + q;
    if (id < 8) {
      int r = id*16 + (lane >> 2);
      srcP[q] = xq + (size_t)(n0 + r)*DF + js;
      dstO[q] = id*1024;
    } else {
      int cr = (id - 8)*16 + (lane >> 2);
      srcP[q] = Bq + (size_t)(c0 + cr)*DF + js;
      dstO[q] = 8192 + (id - 8)*1024;
    }
  }
  const int rsw = (lh ^ ((lr >> 1) & 3)) * 16;
  const int aO = (wm*64 + lr)*64 + rsw;            // + rt*1024
  const int bO = 8192 + (wn*64 + lr)*64 + rsw;     // + ct*1024

  #define STAGE11(slot, tt_) do { \
    _Pragma("unroll") \
    for (int q = 0; q < 3; ++q) \
      GLOAD16(srcP[q] + (tt_)*64, (char*)smem + (slot)*24576 + dstO[q] + ((lane)*16 & 1023)); \
  } while (0)

  STAGE11(0, 0);
  STAGE11(1, 1);

  int slot_r = 0;    // slot holding tile tt
  int slot_s = 2;    // slot to restage with tile tt+2
  for (int tt = 0; tt < 16; ++tt) {
    if (tt < 15) asm volatile("s_waitcnt vmcnt(3)" ::: "memory");
    else         asm volatile("s_waitcnt vmcnt(0)" ::: "memory");
    __builtin_amdgcn_s_barrier();
    if (tt + 2 <= 15) STAGE11(slot_s, tt + 2);

    const char* lb = (const char*)smem + slot_r * 24576;
    l64x2 a2[4], b2[4];
    #pragma unroll
    for (int rt = 0; rt < 4; ++rt) a2[rt] = *(const l64x2*)(lb + aO + rt*1024);
    #pragma unroll
    for (int ct = 0; ct < 4; ++ct) b2[ct] = *(const l64x2*)(lb + bO + ct*1024);
    // no lgkm drain: restaged slot's reads were consumed by last iter's MFMAs

    __builtin_amdgcn_s_setprio(1);
    #pragma unroll
    for (int ct = 0; ct < 4; ++ct)
      #pragma unroll
      for (int rt = 0; rt < 4; ++rt)
        acc[rt][ct] = __builtin_amdgcn_mfma_f32_16x16x32_fp8_fp8(a2[rt][0], b2[ct][0], acc[rt][ct], 0,0,0);
    #pragma unroll
    for (int ct = 0; ct < 4; ++ct)
      #pragma unroll
      for (int rt = 0; rt < 4; ++rt)
        acc[rt][ct] = __builtin_amdgcn_mfma_f32_16x16x32_fp8_fp8(a2[rt][1], b2[ct][1], acc[rt][ct], 0,0,0);
    __builtin_amdgcn_s_setprio(0);

    slot_r = (slot_r == 2) ? 0 : slot_r + 1;
    slot_s = (slot_s == 2) ? 0 : slot_s + 1;
  }

  #pragma unroll
  for (int ct = 0; ct < 4; ++ct) {
    const int comp = cb*16 + wn*4 + ct;
    #pragma unroll
    for (int rt = 0; rt < 4; ++rt) {
      #pragma unroll
      for (int j = 0; j < 4; ++j) {
        float v = acc[rt][ct][j];
        float sq = v*v;
        DPPADD(sq, 0xB1);
        DPPADD(sq, 0x4E);
        DPPADD(sq, 0x124);
        DPPADD(sq, 0x128);
        if (lr == 0) {
          int row = n0 + wm*64 + rt*16 + lh*4 + j;
          size_t idx = (size_t)row * KCOMP + comp;
          out[idx] = out[idx] + 0.5f*sq;
        }
      }
    }
  }
}

// ===========================================================================
// Fallback path (round-2 kernels, needs ~4.8 MB ws) — used if ws too small
// ===========================================================================
#define FB_NG 8
#define FB_CG 288
#define FB_BN 128
#define FB_DT 32
#define FB_PITCH 40
#define FB_BMAT_ELEMS ((size_t)(FB_NG*FB_CG)*DF)
#define FB_CST_OFF (FB_BMAT_ELEMS*2)
#define FB_MUH_OFF (FB_CST_OFF + 512)

__global__ __launch_bounds__(256) void fb_pre(
    const float* __restrict__ PI, const float* __restrict__ MU,
    const float* __restrict__ A, const float* __restrict__ Dm,
    ushort_t* __restrict__ Bmat, float* __restrict__ cst, float* __restrict__ muh)
{
  const int k = blockIdx.x, t = threadIdx.x;
  const int tl = t >> 4, tm = t & 15;
  __shared__ float As[16][16], iDsh[16], MUsh[16];
  __shared__ float R[16][17], rinv[16], zsh[16], bsh[16];
  __shared__ float red[256];

  float accL = 0.f, accb = 0.f, slog = 0.f;
  for (int d0 = 0; d0 < DF; d0 += 16) {
    __syncthreads();
    As[tl][tm] = A[((size_t)k*DF + d0 + tl)*LF + tm];
    if (t < 16) {
      float dv = Dm[k*DF + d0 + t];
      iDsh[t] = 1.f/(dv*dv);
      MUsh[t] = MU[k*DF + d0 + t];
    }
    __syncthreads();
    #pragma unroll
    for (int dd = 0; dd < 16; ++dd)
      accL = fmaf(As[dd][tl]*iDsh[dd], As[dd][tm], accL);
    if (tm == 0) {
      #pragma unroll
      for (int dd = 0; dd < 16; ++dd)
        accb = fmaf(iDsh[dd]*MUsh[dd], As[dd][tl], accb);
    }
    if (t < 16) slog += logf(iDsh[t]);
  }
  __syncthreads();
  R[tl][tm] = accL + (tl == tm ? 1.f : 0.f);
  if (tm == 0) bsh[tl] = accb;
  red[t] = (t < 16) ? slog : 0.f;
  __syncthreads();
  float sumlogiD = 0.f;
  if (t == 0) { for (int i = 0; i < 16; ++i) sumlogiD += red[i]; }

  for (int j = 0; j < 16; ++j) {
    if (t == j) {
      float s = R[j][j];
      for (int i = 0; i < j; ++i) s -= R[j][i]*R[j][i];
      float rj = sqrtf(s);
      R[j][j] = rj; rinv[j] = 1.f/rj;
    }
    __syncthreads();
    if (t < 16 && t > j) {
      float s = R[t][j];
      for (int i = 0; i < j; ++i) s -= R[t][i]*R[j][i];
      R[t][j] = s * rinv[j];
    }
    __syncthreads();
  }

  float ldet = 0.f;
  if (t == 0) {
    #pragma unroll
    for (int j = 0; j < 16; ++j) ldet += 2.f*logf(R[j][j]);
    float w[16], z[16];
    #pragma unroll
    for (int j = 0; j < 16; ++j) {
      float s = bsh[j];
      #pragma unroll
      for (int i = 0; i < 16; ++i) if (i < j) s -= R[j][i]*w[i];
      w[j] = s*rinv[j];
    }
    #pragma unroll
    for (int j = 15; j >= 0; --j) {
      float s = w[j];
      #pragma unroll
      for (int i = 0; i < 16; ++i) if (i > j) s -= R[i][j]*z[i];
      z[j] = s*rinv[j];
      zsh[j] = z[j];
    }
  }
  __syncthreads();

  const int g = k >> 4, kl = k & 15;
  ushort_t* Bgp = Bmat + (size_t)g*FB_CG*DF;
  float muhp = 0.f;
  for (int itr = 0; itr < 4; ++itr) {
    int d = t + itr*256;
    float dv = Dm[k*DF + d];
    float iD = 1.f/(dv*dv);
    float mu = MU[k*DF + d];
    float v[16], gg[16];
    #pragma unroll
    for (int l = 0; l < 16; ++l) v[l] = iD * A[((size_t)k*DF + d)*LF + l];
    #pragma unroll
    for (int j = 0; j < 16; ++j) {
      float s = v[j];
      #pragma unroll
      for (int i = 0; i < 16; ++i) if (i < j) s -= R[j][i]*gg[i];
      gg[j] = s * rinv[j];
    }
    float h = iD*mu;
    #pragma unroll
    for (int l = 0; l < 16; ++l) h -= v[l]*zsh[l];
    muhp = fmaf(mu, h, muhp);
    #pragma unroll
    for (int l = 0; l < 16; ++l)
      Bgp[(size_t)(kl*16 + l)*DF + d] = f2bf(gg[l]);
    Bgp[(size_t)(256 + kl)*DF + d] = f2bf(h);
    Bgp[(size_t)(272 + kl)*DF + d] = f2bf(iD);
  }
  red[t] = muhp;
  __syncthreads();
  for (int s = 128; s > 0; s >>= 1) {
    if (t < s) red[t] += red[t + s];
    __syncthreads();
  }
  if (t == 0) {
    muh[k] = red[0];
    cst[k] = PI[k] - 0.5f*((float)DF*LOG2PI + ldet - sumlogiD);
  }
}

__global__ __launch_bounds__(512, 2) void fb_main(
    const float* __restrict__ x, const ushort_t* __restrict__ Bmat,
    const float* __restrict__ cst, const float* __restrict__ muh,
    float* __restrict__ out)
{
  __shared__ __align__(16) ushort_t smem[2*FB_BN*FB_PITCH + FB_CG*FB_PITCH];
  ushort_t* xs  = smem;
  ushort_t* x2s = smem + FB_BN*FB_PITCH;
  ushort_t* Bs  = smem + 2*FB_BN*FB_PITCH;

  const int t = threadIdx.x;
  const int lane = t & 63, wid = t >> 6;
  const int wr = wid & 3, wc = wid >> 2;
  const int lr = lane & 15, lh = lane >> 4;
  const int n0 = blockIdx.x * FB_BN;
  const int g  = blockIdx.y;

  f32x4 acc[2][9] = {};
  const int srow = t >> 2, sc = t & 3;

  int xoff[2];
  #pragma unroll
  for (int rt = 0; rt < 2; ++rt)
    xoff[rt] = (wr*32 + rt*16 + lr)*FB_PITCH + lh*8;
  int boff[9];
  #pragma unroll
  for (int ct = 0; ct < 9; ++ct)
    boff[ct] = (wc*144 + ct*16 + lr)*FB_PITCH + lh*8;

  for (int d0 = 0; d0 < DF; d0 += FB_DT) {
    __syncthreads();
    {
      const float* xp = x + (size_t)(n0 + srow)*DF + d0 + sc*8;
      float4 v0 = *(const float4*)xp;
      float4 v1 = *(const float4*)(xp + 4);
      float e[8] = {v0.x,v0.y,v0.z,v0.w,v1.x,v1.y,v1.z,v1.w};
      short8v xv, qv;
      #pragma unroll
      for (int i = 0; i < 8; ++i) {
        xv[i] = (short)f2bf(e[i]);
        qv[i] = (short)f2bf(e[i]*e[i]);
      }
      *(short8v*)&xs[srow*FB_PITCH + sc*8]  = xv;
      *(short8v*)&x2s[srow*FB_PITCH + sc*8] = qv;
    }
    for (int u = t; u < FB_CG*4; u += 512) {
      int col = u >> 2, c = u & 3;
      *(short8v*)&Bs[col*FB_PITCH + c*8] =
        *(const short8v*)&Bmat[((size_t)(g*FB_CG + col))*DF + d0 + c*8];
    }
    __syncthreads();

    short8v xf[2];
    #pragma unroll
    for (int rt = 0; rt < 2; ++rt) xf[rt] = *(short8v*)&xs[xoff[rt]];
    #pragma unroll
    for (int ct = 0; ct < 8; ++ct) {
      short8v bfr = *(short8v*)&Bs[boff[ct]];
      #pragma unroll
      for (int rt = 0; rt < 2; ++rt)
        acc[rt][ct] = __builtin_amdgcn_mfma_f32_16x16x32_bf16(xf[rt], bfr, acc[rt][ct], 0, 0, 0);
    }
    {
      short8v bfr = *(short8v*)&Bs[boff[8]];
      short8v a0 = xf[0], a1 = xf[1];
      if (wc) {
        a0 = *(short8v*)&x2s[xoff[0]];
        a1 = *(short8v*)&x2s[xoff[1]];
      }
      acc[0][8] = __builtin_amdgcn_mfma_f32_16x16x32_bf16(a0, bfr, acc[0][8], 0, 0, 0);
      acc[1][8] = __builtin_amdgcn_mfma_f32_16x16x32_bf16(a1, bfr, acc[1][8], 0, 0, 0);
    }
  }

  __syncthreads();
  float* s1v = (float*)smem;
  float* s2h = s1v + FB_BN*17;
  if (wc == 1) {
    #pragma unroll
    for (int rt = 0; rt < 2; ++rt)
      #pragma unroll
      for (int j = 0; j < 4; ++j) {
        int row = wr*32 + rt*16 + lh*4 + j;
        s2h[row*17 + lr] = acc[rt][7][j];
        s1v[row*17 + lr] = acc[rt][8][j];
      }
  }
  __syncthreads();

  const int nyt = wc ? 7 : 9;
  #pragma unroll
  for (int ct = 0; ct < 9; ++ct) {
    if (ct < nyt) {
      int comp = wc*9 + ct;
      int kk = g*16 + comp;
      float cstk = cst[kk], muhk = muh[kk];
      #pragma unroll
      for (int rt = 0; rt < 2; ++rt)
        #pragma unroll
        for (int j = 0; j < 4; ++j) {
          float yv = acc[rt][ct][j];
          float sq = yv*yv;
          sq += __shfl_xor(sq, 1);
          sq += __shfl_xor(sq, 2);
          sq += __shfl_xor(sq, 4);
          sq += __shfl_xor(sq, 8);
          int row = wr*32 + rt*16 + lh*4 + j;
          float s1 = s1v[row*17 + comp];
          float s2 = s2h[row*17 + comp];
          float res = cstk - 0.5f*(s1 - sq - 2.f*s2 + muhk);
          if (lr == 0) out[(size_t)(n0 + row)*KCOMP + kk] = res;
        }
    }
  }
}

// ===========================================================================
extern "C" void kernel_launch(void* const* d_in, const int* in_sizes, int n_in,
                              void* d_out, int out_size, void* d_ws, size_t ws_size,
                              hipStream_t stream) {
  const float* x  = (const float*)d_in[0];
  const float* PI = (const float*)d_in[1];
  const float* MU = (const float*)d_in[2];
  const float* A  = (const float*)d_in[3];
  const float* Dm = (const float*)d_in[4];
  float* out = (float*)d_out;

  if (ws_size >= FULL_NEED) {
    uchar_t* xq   = (uchar_t*)((char*)d_ws + XQ_OFF);
    uchar_t* Bq   = (uchar_t*)((char*)d_ws + BQ_OFF);
    ushort_t* Bsk = (ushort_t*)((char*)d_ws + BSK_OFF);
    float* csk    = (float*)((char*)d_ws + CSK_OFF);

    mfa_pre<<<dim3(KCOMP), dim3(1024), 0, stream>>>(PI, MU, A, Dm, Bq, Bsk, csk);
    mfa_sk6<<<dim3(NPTS/32), dim3(256), 0, stream>>>(x, Bsk, csk, xq, out);
    mfa_gemm11<<<dim3((NPTS/128)*(2048/256)), dim3(512), 0, stream>>>(xq, Bq, out);
  } else {
    ushort_t* Bmat = (ushort_t*)d_ws;
    float* cstp = (float*)((char*)d_ws + FB_CST_OFF);
    float* muhp = (float*)((char*)d_ws + FB_MUH_OFF);
    fb_pre<<<dim3(KCOMP), dim3(256), 0, stream>>>(PI, MU, A, Dm, Bmat, cstp, muhp);
    fb_main<<<dim3(NPTS/FB_BN, FB_NG), dim3(512), 0, stream>>>(x, Bmat, cstp, muhp, out);
  }
}